// Round 2
// baseline (2167.399 us; speedup 1.0000x reference)
//
#include <hip/hip_runtime.h>

#define N_NODES 50000
#define N_EDGES 800000
#define IN_C    256
#define HID_C   128
#define OUT_C   64

// ---------------------------------------------------------------- degree ---
__global__ void deg_kernel(const int* __restrict__ dst,
                           unsigned int* __restrict__ deg, int E) {
    int i = blockIdx.x * blockDim.x + threadIdx.x;
    if (i < E) {
        int d = dst[i];
        if (d >= 0 && d < N_NODES) atomicAdd(&deg[d], 1u);
    }
}

__global__ void dinv_kernel(const unsigned int* __restrict__ deg,
                            float* __restrict__ dinv, int N) {
    int i = blockIdx.x * blockDim.x + threadIdx.x;
    if (i < N) dinv[i] = rsqrtf((float)(deg[i] + 1u));  // +1 = self loop
}

// ------------------------------------------------------------------ GEMM ---
// C[M,NDIM] = A[M,KDIM] @ B[KDIM,NDIM], fp32 (no fp32 MFMA on CDNA4).
// BM x BN tile per block (256 threads), TM x TN micro-tile per thread.
template <int BM, int BN, int BK, int TM, int TN, int KDIM, int NDIM>
__global__ __launch_bounds__(256) void gemm_kernel(
        const float* __restrict__ A, const float* __restrict__ B,
        float* __restrict__ C, int M) {
    __shared__ float As[BK][BM];   // A stored transposed: As[k][row]
    __shared__ float Bs[BK][BN];

    const int t  = threadIdx.x;
    const int tx = t % (BN / TN);
    const int ty = t / (BN / TN);
    const int block_row = blockIdx.x * BM;

    float acc[TM][TN] = {};

    for (int k0 = 0; k0 < KDIM; k0 += BK) {
        // stage A tile (BM x BK), float4 global loads, transposed LDS store
        for (int i = t; i < BM * BK / 4; i += 256) {
            int row = i / (BK / 4);
            int c4  = i % (BK / 4);
            int grow = block_row + row;
            if (grow >= M) grow = M - 1;  // clamp; garbage rows never stored
            float4 v = *(const float4*)&A[(size_t)grow * KDIM + k0 + c4 * 4];
            As[c4 * 4 + 0][row] = v.x;
            As[c4 * 4 + 1][row] = v.y;
            As[c4 * 4 + 2][row] = v.z;
            As[c4 * 4 + 3][row] = v.w;
        }
        // stage B tile (BK x BN)
        for (int i = t; i < BK * BN / 4; i += 256) {
            int row = i / (BN / 4);
            int c4  = i % (BN / 4);
            *(float4*)&Bs[row][c4 * 4] =
                *(const float4*)&B[(size_t)(k0 + row) * NDIM + c4 * 4];
        }
        __syncthreads();

#pragma unroll
        for (int kk = 0; kk < BK; ++kk) {
            float4 av = *(const float4*)&As[kk][ty * TM];   // TM == 4
            float a_[4] = {av.x, av.y, av.z, av.w};
            float4 bv[TN / 4];
#pragma unroll
            for (int j4 = 0; j4 < TN / 4; ++j4)
                bv[j4] = *(const float4*)&Bs[kk][tx * TN + j4 * 4];
#pragma unroll
            for (int i = 0; i < TM; ++i) {
                float ai = a_[i];
#pragma unroll
                for (int j4 = 0; j4 < TN / 4; ++j4) {
                    acc[i][j4 * 4 + 0] = fmaf(ai, bv[j4].x, acc[i][j4 * 4 + 0]);
                    acc[i][j4 * 4 + 1] = fmaf(ai, bv[j4].y, acc[i][j4 * 4 + 1]);
                    acc[i][j4 * 4 + 2] = fmaf(ai, bv[j4].z, acc[i][j4 * 4 + 2]);
                    acc[i][j4 * 4 + 3] = fmaf(ai, bv[j4].w, acc[i][j4 * 4 + 3]);
                }
            }
        }
        __syncthreads();
    }

#pragma unroll
    for (int i = 0; i < TM; ++i) {
        int grow = block_row + ty * TM + i;
        if (grow < M) {
#pragma unroll
            for (int j4 = 0; j4 < TN / 4; ++j4) {
                float4 v = {acc[i][j4 * 4 + 0], acc[i][j4 * 4 + 1],
                            acc[i][j4 * 4 + 2], acc[i][j4 * 4 + 3]};
                *(float4*)&C[(size_t)grow * NDIM + tx * TN + j4 * 4] = v;
            }
        }
    }
}

// --------------------------------------------------------------- scatter ---
// For each edge e: out[dst[e], :] += h[src[e], :] * dinv[src]*dinv[dst]
// C4 = channels/4; C4 consecutive threads handle one edge (float4 each).
template <int C, int C4>
__global__ void scatter_kernel(const int* __restrict__ src,
                               const int* __restrict__ dst,
                               const float* __restrict__ dinv,
                               const float* __restrict__ h,
                               float* __restrict__ out, int E) {
    int tid  = blockIdx.x * blockDim.x + threadIdx.x;
    int e    = tid / C4;
    int lane = tid % C4;
    if (e >= E) return;
    int s = src[e];
    int d = dst[e];
    if ((unsigned)s >= N_NODES || (unsigned)d >= N_NODES) return;  // safety
    float norm = dinv[s] * dinv[d];
    float4 v = *(const float4*)&h[(size_t)s * C + lane * 4];
    float* o = &out[(size_t)d * C + lane * 4];
    unsafeAtomicAdd(o + 0, v.x * norm);
    unsafeAtomicAdd(o + 1, v.y * norm);
    unsafeAtomicAdd(o + 2, v.z * norm);
    unsafeAtomicAdd(o + 3, v.w * norm);
}

// -------------------------------------------------------------- epilogue ---
// out[v,c] = (agg[v,c] + h[v,c]*dinv[v]^2 + bias[c]), optional ReLU.
// Self-loop term folded in here (no atomics needed for it).
template <int C, bool RELU>
__global__ void epilogue_kernel(const float* __restrict__ agg,
                                const float* __restrict__ h,
                                const float* __restrict__ dinv,
                                const float* __restrict__ bias,
                                float* __restrict__ out, int N) {
    int tid = blockIdx.x * blockDim.x + threadIdx.x;
    int total = N * (C / 4);
    if (tid >= total) return;
    int row = tid / (C / 4);
    int c4  = tid % (C / 4);
    float d2 = dinv[row];
    d2 *= d2;
    float4 a  = *(const float4*)&agg[(size_t)tid * 4];
    float4 hv = *(const float4*)&h[(size_t)tid * 4];
    float4 b  = *(const float4*)&bias[c4 * 4];
    float4 r;
    r.x = a.x + hv.x * d2 + b.x;
    r.y = a.y + hv.y * d2 + b.y;
    r.z = a.z + hv.z * d2 + b.z;
    r.w = a.w + hv.w * d2 + b.w;
    if (RELU) {
        r.x = fmaxf(r.x, 0.f);
        r.y = fmaxf(r.y, 0.f);
        r.z = fmaxf(r.z, 0.f);
        r.w = fmaxf(r.w, 0.f);
    }
    *(float4*)&out[(size_t)tid * 4] = r;
}

// ---------------------------------------------------------------- launch ---
extern "C" void kernel_launch(void* const* d_in, const int* in_sizes, int n_in,
                              void* d_out, int out_size, void* d_ws, size_t ws_size,
                              hipStream_t stream) {
    const float* x   = (const float*)d_in[0];
    const int*   ei  = (const int*)d_in[1];   // int32 per harness contract
    const float* W1  = (const float*)d_in[2];
    const float* b1  = (const float*)d_in[3];
    const float* W2  = (const float*)d_in[4];
    const float* b2  = (const float*)d_in[5];
    float*       out = (float*)d_out;

    const int* src = ei;            // edge_index[0]
    const int* dst = ei + N_EDGES;  // edge_index[1]

    // workspace carve-up (256B aligned)
    char* ws = (char*)d_ws;
    size_t off = 0;
    auto alloc = [&](size_t bytes) {
        void* p = ws + off;
        off += (bytes + 255) & ~(size_t)255;
        return p;
    };
    unsigned int* deg  = (unsigned int*)alloc(N_NODES * sizeof(unsigned int));
    float*        dinv = (float*)alloc(N_NODES * sizeof(float));
    float*        h1   = (float*)alloc((size_t)N_NODES * HID_C * sizeof(float)); // reused as h2
    float*        agg1 = (float*)alloc((size_t)N_NODES * HID_C * sizeof(float));
    float*        h2   = h1;  // layer-1 h no longer needed once epilogue1 ran

    // zero-init accumulators (graph-capture-safe async memsets)
    hipMemsetAsync(deg, 0, N_NODES * sizeof(unsigned int), stream);
    hipMemsetAsync(agg1, 0, (size_t)N_NODES * HID_C * sizeof(float), stream);
    hipMemsetAsync(out, 0, (size_t)N_NODES * OUT_C * sizeof(float), stream);

    // degree + normalization
    deg_kernel<<<(N_EDGES + 255) / 256, 256, 0, stream>>>(dst, deg, N_EDGES);
    dinv_kernel<<<(N_NODES + 255) / 256, 256, 0, stream>>>(deg, dinv, N_NODES);

    // ---- layer 1 ----
    // h1 = x @ W1   [50000,256]x[256,128]
    gemm_kernel<64, 128, 32, 4, 8, IN_C, HID_C>
        <<<dim3((N_NODES + 63) / 64, 1), 256, 0, stream>>>(x, W1, h1, N_NODES);
    // agg1 += scatter(h1)
    {
        long long total = (long long)N_EDGES * (HID_C / 4);
        scatter_kernel<HID_C, HID_C / 4>
            <<<(unsigned)((total + 255) / 256), 256, 0, stream>>>(
                src, dst, dinv, h1, agg1, N_EDGES);
    }
    // agg1 = relu(agg1 + h1*dinv^2 + b1)   (in place)
    {
        int total = N_NODES * (HID_C / 4);
        epilogue_kernel<HID_C, true>
            <<<(total + 255) / 256, 256, 0, stream>>>(agg1, h1, dinv, b1, agg1,
                                                      N_NODES);
    }

    // ---- layer 2 ----
    // h2 = agg1 @ W2   [50000,128]x[128,64]
    gemm_kernel<64, 64, 32, 4, 4, HID_C, OUT_C>
        <<<dim3((N_NODES + 63) / 64, 1), 256, 0, stream>>>(agg1, W2, h2, N_NODES);
    // out += scatter(h2)
    {
        long long total = (long long)N_EDGES * (OUT_C / 4);
        scatter_kernel<OUT_C, OUT_C / 4>
            <<<(unsigned)((total + 255) / 256), 256, 0, stream>>>(
                src, dst, dinv, h2, out, N_EDGES);
    }
    // out = out + h2*dinv^2 + b2   (in place, no relu)
    {
        int total = N_NODES * (OUT_C / 4);
        epilogue_kernel<OUT_C, false>
            <<<(total + 255) / 256, 256, 0, stream>>>(out, h2, dinv, b2, out,
                                                      N_NODES);
    }
}

// Round 3
// 352.298 us; speedup vs baseline: 6.1522x; 6.1522x over previous
//
#include <hip/hip_runtime.h>

#define N_NODES 50000
#define N_EDGES 800000
#define IN_C    256
#define HID_C   128
#define OUT_C   64

// ---------------------------------------------------------------- degree ---
__global__ void deg_kernel(const int* __restrict__ dst,
                           unsigned int* __restrict__ deg, int E) {
    int i = blockIdx.x * blockDim.x + threadIdx.x;
    if (i < E) {
        int d = dst[i];
        if ((unsigned)d < N_NODES) atomicAdd(&deg[d], 1u);
    }
}

__global__ void dinv_kernel(const unsigned int* __restrict__ deg,
                            float* __restrict__ dinv, int N) {
    int i = blockIdx.x * blockDim.x + threadIdx.x;
    if (i < N) dinv[i] = rsqrtf((float)(deg[i] + 1u));  // +1 = self loop
}

// ------------------------------------------------------------------ scan ---
// In-place exclusive scan of cur[0..N): counts -> start offsets.
// Single block of 1024 threads; each thread owns a contiguous chunk.
__global__ __launch_bounds__(1024) void scan_kernel(unsigned int* cur, int N) {
    __shared__ unsigned int part[1024];
    const int t = threadIdx.x;
    const int PER = (N + 1023) / 1024;
    int lo = t * PER;
    int hi = lo + PER; if (hi > N) hi = N;
    unsigned int s = 0;
    for (int i = lo; i < hi; ++i) s += cur[i];
    part[t] = s;
    __syncthreads();
    for (int off = 1; off < 1024; off <<= 1) {
        unsigned int v = (t >= off) ? part[t - off] : 0u;
        __syncthreads();
        part[t] += v;
        __syncthreads();
    }
    unsigned int run = (t == 0) ? 0u : part[t - 1];
    for (int i = lo; i < hi; ++i) {
        unsigned int c = cur[i];
        cur[i] = run;
        run += c;
    }
}

// ------------------------------------------------------------------ fill ---
// Bucket edges by dst. After this kernel, cur[v] == end(v) (== start(v+1)).
__global__ void fill_kernel(const int* __restrict__ src,
                            const int* __restrict__ dst,
                            unsigned int* __restrict__ cur,
                            int* __restrict__ esrc, int E) {
    int i = blockIdx.x * blockDim.x + threadIdx.x;
    if (i < E) {
        int s = src[i];
        int d = dst[i];
        if ((unsigned)s >= N_NODES || (unsigned)d >= N_NODES) return;
        unsigned int pos = atomicAdd(&cur[d], 1u);
        esrc[pos] = s;
    }
}

// ------------------------------------------------------------------ GEMM ---
template <int BM, int BN, int BK, int TM, int TN, int KDIM, int NDIM>
__global__ __launch_bounds__(256) void gemm_kernel(
        const float* __restrict__ A, const float* __restrict__ B,
        float* __restrict__ C, int M) {
    __shared__ float As[BK][BM];   // A transposed in LDS
    __shared__ float Bs[BK][BN];

    const int t  = threadIdx.x;
    const int tx = t % (BN / TN);
    const int ty = t / (BN / TN);
    const int block_row = blockIdx.x * BM;

    float acc[TM][TN] = {};

    for (int k0 = 0; k0 < KDIM; k0 += BK) {
        for (int i = t; i < BM * BK / 4; i += 256) {
            int row = i / (BK / 4);
            int c4  = i % (BK / 4);
            int grow = block_row + row;
            if (grow >= M) grow = M - 1;
            float4 v = *(const float4*)&A[(size_t)grow * KDIM + k0 + c4 * 4];
            As[c4 * 4 + 0][row] = v.x;
            As[c4 * 4 + 1][row] = v.y;
            As[c4 * 4 + 2][row] = v.z;
            As[c4 * 4 + 3][row] = v.w;
        }
        for (int i = t; i < BK * BN / 4; i += 256) {
            int row = i / (BN / 4);
            int c4  = i % (BN / 4);
            *(float4*)&Bs[row][c4 * 4] =
                *(const float4*)&B[(size_t)(k0 + row) * NDIM + c4 * 4];
        }
        __syncthreads();

#pragma unroll
        for (int kk = 0; kk < BK; ++kk) {
            float4 av = *(const float4*)&As[kk][ty * TM];
            float a_[4] = {av.x, av.y, av.z, av.w};
            float4 bv[TN / 4];
#pragma unroll
            for (int j4 = 0; j4 < TN / 4; ++j4)
                bv[j4] = *(const float4*)&Bs[kk][tx * TN + j4 * 4];
#pragma unroll
            for (int i = 0; i < TM; ++i) {
                float ai = a_[i];
#pragma unroll
                for (int j4 = 0; j4 < TN / 4; ++j4) {
                    acc[i][j4 * 4 + 0] = fmaf(ai, bv[j4].x, acc[i][j4 * 4 + 0]);
                    acc[i][j4 * 4 + 1] = fmaf(ai, bv[j4].y, acc[i][j4 * 4 + 1]);
                    acc[i][j4 * 4 + 2] = fmaf(ai, bv[j4].z, acc[i][j4 * 4 + 2]);
                    acc[i][j4 * 4 + 3] = fmaf(ai, bv[j4].w, acc[i][j4 * 4 + 3]);
                }
            }
        }
        __syncthreads();
    }

#pragma unroll
    for (int i = 0; i < TM; ++i) {
        int grow = block_row + ty * TM + i;
        if (grow < M) {
#pragma unroll
            for (int j4 = 0; j4 < TN / 4; ++j4) {
                float4 v = {acc[i][j4 * 4 + 0], acc[i][j4 * 4 + 1],
                            acc[i][j4 * 4 + 2], acc[i][j4 * 4 + 3]};
                *(float4*)&C[(size_t)grow * NDIM + tx * TN + j4 * 4] = v;
            }
        }
    }
}

// ---------------------------------------------------------------- gather ---
// out[v] = dinv[v]*(sum_{s in in(v)} dinv[s]*h[s]) + dinv[v]^2*h[v] + bias
// G = C/4 lanes per node, one float4 per lane. No atomics: each output row
// is written exactly once. Self-loop + bias + optional ReLU fused.
template <int C, bool RELU>
__global__ __launch_bounds__(256) void gather_kernel(
        const unsigned int* __restrict__ cur,   // ends after fill
        const int* __restrict__ esrc,
        const float* __restrict__ dinv,
        const float* __restrict__ h,
        const float* __restrict__ bias,
        float* __restrict__ out, int N) {
    constexpr int G = C / 4;
    int tid  = blockIdx.x * blockDim.x + threadIdx.x;
    int v    = tid / G;
    int lane = tid % G;
    if (v >= N) return;
    unsigned int start = (v == 0) ? 0u : cur[v - 1];
    unsigned int end   = cur[v];
    float4 acc = {0.f, 0.f, 0.f, 0.f};
    for (unsigned int e = start; e < end; ++e) {
        int s   = esrc[e];
        float w = dinv[s];
        float4 hv = *(const float4*)&h[(size_t)s * C + lane * 4];
        acc.x = fmaf(w, hv.x, acc.x);
        acc.y = fmaf(w, hv.y, acc.y);
        acc.z = fmaf(w, hv.z, acc.z);
        acc.w = fmaf(w, hv.w, acc.w);
    }
    float dv  = dinv[v];
    float dv2 = dv * dv;
    float4 hv = *(const float4*)&h[(size_t)v * C + lane * 4];
    float4 b  = *(const float4*)&bias[lane * 4];
    float4 r;
    r.x = fmaf(dv, acc.x, fmaf(dv2, hv.x, b.x));
    r.y = fmaf(dv, acc.y, fmaf(dv2, hv.y, b.y));
    r.z = fmaf(dv, acc.z, fmaf(dv2, hv.z, b.z));
    r.w = fmaf(dv, acc.w, fmaf(dv2, hv.w, b.w));
    if (RELU) {
        r.x = fmaxf(r.x, 0.f);
        r.y = fmaxf(r.y, 0.f);
        r.z = fmaxf(r.z, 0.f);
        r.w = fmaxf(r.w, 0.f);
    }
    *(float4*)&out[(size_t)v * C + lane * 4] = r;
}

// ------------------------------------------- fallback path (atomics) ------
template <int C, int C4>
__global__ void scatter_kernel(const int* __restrict__ src,
                               const int* __restrict__ dst,
                               const float* __restrict__ dinv,
                               const float* __restrict__ h,
                               float* __restrict__ out, int E) {
    int tid  = blockIdx.x * blockDim.x + threadIdx.x;
    int e    = tid / C4;
    int lane = tid % C4;
    if (e >= E) return;
    int s = src[e];
    int d = dst[e];
    if ((unsigned)s >= N_NODES || (unsigned)d >= N_NODES) return;
    float norm = dinv[s] * dinv[d];
    float4 v = *(const float4*)&h[(size_t)s * C + lane * 4];
    float* o = &out[(size_t)d * C + lane * 4];
    unsafeAtomicAdd(o + 0, v.x * norm);
    unsafeAtomicAdd(o + 1, v.y * norm);
    unsafeAtomicAdd(o + 2, v.z * norm);
    unsafeAtomicAdd(o + 3, v.w * norm);
}

template <int C, bool RELU>
__global__ void epilogue_kernel(const float* __restrict__ agg,
                                const float* __restrict__ h,
                                const float* __restrict__ dinv,
                                const float* __restrict__ bias,
                                float* __restrict__ out, int N) {
    int tid = blockIdx.x * blockDim.x + threadIdx.x;
    int total = N * (C / 4);
    if (tid >= total) return;
    int c4  = tid % (C / 4);
    int row = tid / (C / 4);
    float d2 = dinv[row];
    d2 *= d2;
    float4 a  = *(const float4*)&agg[(size_t)tid * 4];
    float4 hv = *(const float4*)&h[(size_t)tid * 4];
    float4 b  = *(const float4*)&bias[c4 * 4];
    float4 r;
    r.x = a.x + hv.x * d2 + b.x;
    r.y = a.y + hv.y * d2 + b.y;
    r.z = a.z + hv.z * d2 + b.z;
    r.w = a.w + hv.w * d2 + b.w;
    if (RELU) {
        r.x = fmaxf(r.x, 0.f);
        r.y = fmaxf(r.y, 0.f);
        r.z = fmaxf(r.z, 0.f);
        r.w = fmaxf(r.w, 0.f);
    }
    *(float4*)&out[(size_t)tid * 4] = r;
}

// ---------------------------------------------------------------- launch ---
extern "C" void kernel_launch(void* const* d_in, const int* in_sizes, int n_in,
                              void* d_out, int out_size, void* d_ws, size_t ws_size,
                              hipStream_t stream) {
    const float* x   = (const float*)d_in[0];
    const int*   ei  = (const int*)d_in[1];
    const float* W1  = (const float*)d_in[2];
    const float* b1  = (const float*)d_in[3];
    const float* W2  = (const float*)d_in[4];
    const float* b2  = (const float*)d_in[5];
    float*       out = (float*)d_out;

    const int* src = ei;
    const int* dst = ei + N_EDGES;

    char* ws = (char*)d_ws;
    size_t off = 0;
    auto alloc = [&](size_t bytes) {
        void* p = ws + off;
        off += (bytes + 255) & ~(size_t)255;
        return p;
    };

    // --- CSR-gather path layout ---
    unsigned int* cur  = (unsigned int*)alloc(N_NODES * sizeof(unsigned int));
    float*        dinv = (float*)alloc(N_NODES * sizeof(float));
    int*          esrc = (int*)alloc((size_t)N_EDGES * sizeof(int));
    float*        h1   = (float*)alloc((size_t)N_NODES * HID_C * sizeof(float));
    float*        g1   = (float*)alloc((size_t)N_NODES * HID_C * sizeof(float));
    float*        h2   = h1;  // layer-2 GEMM output reuses h1's space
    size_t needed = off;

    if (ws_size >= needed) {
        // ---------------- CSR gather path (no float atomics) ----------------
        hipMemsetAsync(cur, 0, N_NODES * sizeof(unsigned int), stream);

        deg_kernel<<<(N_EDGES + 255) / 256, 256, 0, stream>>>(dst, cur, N_EDGES);
        dinv_kernel<<<(N_NODES + 255) / 256, 256, 0, stream>>>(cur, dinv, N_NODES);
        scan_kernel<<<1, 1024, 0, stream>>>(cur, N_NODES);          // counts->starts
        fill_kernel<<<(N_EDGES + 255) / 256, 256, 0, stream>>>(src, dst, cur,
                                                               esrc, N_EDGES);
        // layer 1
        gemm_kernel<64, 128, 32, 4, 8, IN_C, HID_C>
            <<<(N_NODES + 63) / 64, 256, 0, stream>>>(x, W1, h1, N_NODES);
        {
            int total = N_NODES * (HID_C / 4);
            gather_kernel<HID_C, true>
                <<<(total + 255) / 256, 256, 0, stream>>>(cur, esrc, dinv, h1,
                                                          b1, g1, N_NODES);
        }
        // layer 2
        gemm_kernel<64, 64, 32, 4, 4, HID_C, OUT_C>
            <<<(N_NODES + 63) / 64, 256, 0, stream>>>(g1, W2, h2, N_NODES);
        {
            int total = N_NODES * (OUT_C / 4);
            gather_kernel<OUT_C, false>
                <<<(total + 255) / 256, 256, 0, stream>>>(cur, esrc, dinv, h2,
                                                          b2, out, N_NODES);
        }
    } else {
        // ---------------- fallback: proven atomic-scatter path --------------
        off = 0;
        unsigned int* deg   = (unsigned int*)alloc(N_NODES * sizeof(unsigned int));
        float*        dinvF = (float*)alloc(N_NODES * sizeof(float));
        float*        h1F   = (float*)alloc((size_t)N_NODES * HID_C * sizeof(float));
        float*        agg1  = (float*)alloc((size_t)N_NODES * HID_C * sizeof(float));
        float*        h2F   = h1F;

        hipMemsetAsync(deg, 0, N_NODES * sizeof(unsigned int), stream);
        hipMemsetAsync(agg1, 0, (size_t)N_NODES * HID_C * sizeof(float), stream);
        hipMemsetAsync(out, 0, (size_t)N_NODES * OUT_C * sizeof(float), stream);

        deg_kernel<<<(N_EDGES + 255) / 256, 256, 0, stream>>>(dst, deg, N_EDGES);
        dinv_kernel<<<(N_NODES + 255) / 256, 256, 0, stream>>>(deg, dinvF, N_NODES);

        gemm_kernel<64, 128, 32, 4, 8, IN_C, HID_C>
            <<<(N_NODES + 63) / 64, 256, 0, stream>>>(x, W1, h1F, N_NODES);
        {
            long long total = (long long)N_EDGES * (HID_C / 4);
            scatter_kernel<HID_C, HID_C / 4>
                <<<(unsigned)((total + 255) / 256), 256, 0, stream>>>(
                    src, dst, dinvF, h1F, agg1, N_EDGES);
        }
        {
            int total = N_NODES * (HID_C / 4);
            epilogue_kernel<HID_C, true>
                <<<(total + 255) / 256, 256, 0, stream>>>(agg1, h1F, dinvF, b1,
                                                          agg1, N_NODES);
        }
        gemm_kernel<64, 64, 32, 4, 4, HID_C, OUT_C>
            <<<(N_NODES + 63) / 64, 256, 0, stream>>>(agg1, W2, h2F, N_NODES);
        {
            long long total = (long long)N_EDGES * (OUT_C / 4);
            scatter_kernel<OUT_C, OUT_C / 4>
                <<<(unsigned)((total + 255) / 256), 256, 0, stream>>>(
                    src, dst, dinvF, h2F, out, N_EDGES);
        }
        {
            int total = N_NODES * (OUT_C / 4);
            epilogue_kernel<OUT_C, false>
                <<<(total + 255) / 256, 256, 0, stream>>>(out, h2F, dinvF, b2,
                                                          out, N_NODES);
        }
    }
}

// Round 4
// 276.281 us; speedup vs baseline: 7.8449x; 1.2751x over previous
//
#include <hip/hip_runtime.h>

#define N_NODES 50000
#define N_EDGES 800000
#define IN_C    256
#define HID_C   128
#define OUT_C   64

#define SCAN_CHUNK 512
#define SCAN_NB ((N_NODES + SCAN_CHUNK - 1) / SCAN_CHUNK)   // 98 (<= 256)

// ---------------------------------------------------------------- degree ---
__global__ void deg_kernel(const int* __restrict__ dst,
                           unsigned int* __restrict__ deg, int E) {
    int i = blockIdx.x * blockDim.x + threadIdx.x;
    if (i < E) {
        int d = dst[i];
        if ((unsigned)d < N_NODES) atomicAdd(&deg[d], 1u);
    }
}

// ------------------------------------------------------------------ scan ---
// Phase 1: per-block (512-elem chunk) exclusive scan + block sum.
// Also fuses dinv = rsqrt(deg+1) since we're reading the counts anyway.
__global__ __launch_bounds__(256) void scan1_kernel(
        unsigned int* __restrict__ cur, unsigned int* __restrict__ bsum,
        float* __restrict__ dinv, int N) {
    __shared__ unsigned int lds[256];
    const int b = blockIdx.x;
    const int t = threadIdx.x;
    const int i0 = b * SCAN_CHUNK + 2 * t;

    unsigned e0 = (i0     < N) ? cur[i0]     : 0u;
    unsigned e1 = (i0 + 1 < N) ? cur[i0 + 1] : 0u;
    if (i0     < N) dinv[i0]     = rsqrtf((float)(e0 + 1u));
    if (i0 + 1 < N) dinv[i0 + 1] = rsqrtf((float)(e1 + 1u));

    unsigned p = e0 + e1;
    lds[t] = p;
    __syncthreads();
    // Hillis-Steele inclusive scan over 256 partials
    for (int off = 1; off < 256; off <<= 1) {
        unsigned v = (t >= off) ? lds[t - off] : 0u;
        __syncthreads();
        lds[t] += v;
        __syncthreads();
    }
    unsigned excl = lds[t] - p;   // exclusive prefix within block
    if (t == 255) bsum[b] = lds[255];
    if (i0     < N) cur[i0]     = excl;
    if (i0 + 1 < N) cur[i0 + 1] = excl + e0;
}

// Phase 2: block b adds sum(bsum[0..b)) to its chunk. nb <= 256.
__global__ __launch_bounds__(256) void scan2_kernel(
        unsigned int* __restrict__ cur, const unsigned int* __restrict__ bsum,
        int N) {
    __shared__ unsigned int lds[256];
    const int b = blockIdx.x;
    const int t = threadIdx.x;
    lds[t] = (t < b && t < SCAN_NB) ? bsum[t] : 0u;
    __syncthreads();
    for (int off = 128; off > 0; off >>= 1) {
        if (t < off) lds[t] += lds[t + off];
        __syncthreads();
    }
    const unsigned offset = lds[0];
    const int i0 = b * SCAN_CHUNK + 2 * t;
    if (i0     < N) cur[i0]     += offset;
    if (i0 + 1 < N) cur[i0 + 1] += offset;
}

// ------------------------------------------------------------------ fill ---
// Bucket edges by dst. After this kernel, cur[v] == end(v) (== start(v+1)).
__global__ void fill_kernel(const int* __restrict__ src,
                            const int* __restrict__ dst,
                            unsigned int* __restrict__ cur,
                            int* __restrict__ esrc, int E) {
    int i = blockIdx.x * blockDim.x + threadIdx.x;
    if (i < E) {
        int s = src[i];
        int d = dst[i];
        if ((unsigned)s >= N_NODES || (unsigned)d >= N_NODES) return;
        unsigned int pos = atomicAdd(&cur[d], 1u);
        esrc[pos] = s;
    }
}

// ------------------------------------------------------------------ GEMM ---
template <int BM, int BN, int BK, int TM, int TN, int KDIM, int NDIM>
__global__ __launch_bounds__(256) void gemm_kernel(
        const float* __restrict__ A, const float* __restrict__ B,
        float* __restrict__ C, int M) {
    __shared__ float As[BK][BM];   // A transposed in LDS
    __shared__ float Bs[BK][BN];

    const int t  = threadIdx.x;
    const int tx = t % (BN / TN);
    const int ty = t / (BN / TN);
    const int block_row = blockIdx.x * BM;

    float acc[TM][TN] = {};

    for (int k0 = 0; k0 < KDIM; k0 += BK) {
        for (int i = t; i < BM * BK / 4; i += 256) {
            int row = i / (BK / 4);
            int c4  = i % (BK / 4);
            int grow = block_row + row;
            if (grow >= M) grow = M - 1;
            float4 v = *(const float4*)&A[(size_t)grow * KDIM + k0 + c4 * 4];
            As[c4 * 4 + 0][row] = v.x;
            As[c4 * 4 + 1][row] = v.y;
            As[c4 * 4 + 2][row] = v.z;
            As[c4 * 4 + 3][row] = v.w;
        }
        for (int i = t; i < BK * BN / 4; i += 256) {
            int row = i / (BN / 4);
            int c4  = i % (BN / 4);
            *(float4*)&Bs[row][c4 * 4] =
                *(const float4*)&B[(size_t)(k0 + row) * NDIM + c4 * 4];
        }
        __syncthreads();

#pragma unroll
        for (int kk = 0; kk < BK; ++kk) {
            float4 av = *(const float4*)&As[kk][ty * TM];
            float a_[4] = {av.x, av.y, av.z, av.w};
            float4 bv[TN / 4];
#pragma unroll
            for (int j4 = 0; j4 < TN / 4; ++j4)
                bv[j4] = *(const float4*)&Bs[kk][tx * TN + j4 * 4];
#pragma unroll
            for (int i = 0; i < TM; ++i) {
                float ai = a_[i];
#pragma unroll
                for (int j4 = 0; j4 < TN / 4; ++j4) {
                    acc[i][j4 * 4 + 0] = fmaf(ai, bv[j4].x, acc[i][j4 * 4 + 0]);
                    acc[i][j4 * 4 + 1] = fmaf(ai, bv[j4].y, acc[i][j4 * 4 + 1]);
                    acc[i][j4 * 4 + 2] = fmaf(ai, bv[j4].z, acc[i][j4 * 4 + 2]);
                    acc[i][j4 * 4 + 3] = fmaf(ai, bv[j4].w, acc[i][j4 * 4 + 3]);
                }
            }
        }
        __syncthreads();
    }

#pragma unroll
    for (int i = 0; i < TM; ++i) {
        int grow = block_row + ty * TM + i;
        if (grow < M) {
#pragma unroll
            for (int j4 = 0; j4 < TN / 4; ++j4) {
                float4 v = {acc[i][j4 * 4 + 0], acc[i][j4 * 4 + 1],
                            acc[i][j4 * 4 + 2], acc[i][j4 * 4 + 3]};
                *(float4*)&C[(size_t)grow * NDIM + tx * TN + j4 * 4] = v;
            }
        }
    }
}

// ---------------------------------------------------------------- gather ---
// out[v] = dinv[v]*(sum_{s in in(v)} dinv[s]*h[s]) + dinv[v]^2*h[v] + bias
template <int C, bool RELU>
__global__ __launch_bounds__(256) void gather_kernel(
        const unsigned int* __restrict__ cur,   // ends after fill
        const int* __restrict__ esrc,
        const float* __restrict__ dinv,
        const float* __restrict__ h,
        const float* __restrict__ bias,
        float* __restrict__ out, int N) {
    constexpr int G = C / 4;
    int tid  = blockIdx.x * blockDim.x + threadIdx.x;
    int v    = tid / G;
    int lane = tid % G;
    if (v >= N) return;
    unsigned int start = (v == 0) ? 0u : cur[v - 1];
    unsigned int end   = cur[v];
    float4 acc = {0.f, 0.f, 0.f, 0.f};
    for (unsigned int e = start; e < end; ++e) {
        int s   = esrc[e];
        float w = dinv[s];
        float4 hv = *(const float4*)&h[(size_t)s * C + lane * 4];
        acc.x = fmaf(w, hv.x, acc.x);
        acc.y = fmaf(w, hv.y, acc.y);
        acc.z = fmaf(w, hv.z, acc.z);
        acc.w = fmaf(w, hv.w, acc.w);
    }
    float dv  = dinv[v];
    float dv2 = dv * dv;
    float4 hv = *(const float4*)&h[(size_t)v * C + lane * 4];
    float4 b  = *(const float4*)&bias[lane * 4];
    float4 r;
    r.x = fmaf(dv, acc.x, fmaf(dv2, hv.x, b.x));
    r.y = fmaf(dv, acc.y, fmaf(dv2, hv.y, b.y));
    r.z = fmaf(dv, acc.z, fmaf(dv2, hv.z, b.z));
    r.w = fmaf(dv, acc.w, fmaf(dv2, hv.w, b.w));
    if (RELU) {
        r.x = fmaxf(r.x, 0.f);
        r.y = fmaxf(r.y, 0.f);
        r.z = fmaxf(r.z, 0.f);
        r.w = fmaxf(r.w, 0.f);
    }
    *(float4*)&out[(size_t)v * C + lane * 4] = r;
}

// ------------------------------------------- fallback path (atomics) ------
template <int C, int C4>
__global__ void scatter_kernel(const int* __restrict__ src,
                               const int* __restrict__ dst,
                               const float* __restrict__ dinv,
                               const float* __restrict__ h,
                               float* __restrict__ out, int E) {
    int tid  = blockIdx.x * blockDim.x + threadIdx.x;
    int e    = tid / C4;
    int lane = tid % C4;
    if (e >= E) return;
    int s = src[e];
    int d = dst[e];
    if ((unsigned)s >= N_NODES || (unsigned)d >= N_NODES) return;
    float norm = dinv[s] * dinv[d];
    float4 v = *(const float4*)&h[(size_t)s * C + lane * 4];
    float* o = &out[(size_t)d * C + lane * 4];
    unsafeAtomicAdd(o + 0, v.x * norm);
    unsafeAtomicAdd(o + 1, v.y * norm);
    unsafeAtomicAdd(o + 2, v.z * norm);
    unsafeAtomicAdd(o + 3, v.w * norm);
}

__global__ void dinv_only_kernel(const unsigned int* __restrict__ deg,
                                 float* __restrict__ dinv, int N) {
    int i = blockIdx.x * blockDim.x + threadIdx.x;
    if (i < N) dinv[i] = rsqrtf((float)(deg[i] + 1u));
}

template <int C, bool RELU>
__global__ void epilogue_kernel(const float* __restrict__ agg,
                                const float* __restrict__ h,
                                const float* __restrict__ dinv,
                                const float* __restrict__ bias,
                                float* __restrict__ out, int N) {
    int tid = blockIdx.x * blockDim.x + threadIdx.x;
    int total = N * (C / 4);
    if (tid >= total) return;
    int c4  = tid % (C / 4);
    int row = tid / (C / 4);
    float d2 = dinv[row];
    d2 *= d2;
    float4 a  = *(const float4*)&agg[(size_t)tid * 4];
    float4 hv = *(const float4*)&h[(size_t)tid * 4];
    float4 b  = *(const float4*)&bias[c4 * 4];
    float4 r;
    r.x = a.x + hv.x * d2 + b.x;
    r.y = a.y + hv.y * d2 + b.y;
    r.z = a.z + hv.z * d2 + b.z;
    r.w = a.w + hv.w * d2 + b.w;
    if (RELU) {
        r.x = fmaxf(r.x, 0.f);
        r.y = fmaxf(r.y, 0.f);
        r.z = fmaxf(r.z, 0.f);
        r.w = fmaxf(r.w, 0.f);
    }
    *(float4*)&out[(size_t)tid * 4] = r;
}

// ---------------------------------------------------------------- launch ---
extern "C" void kernel_launch(void* const* d_in, const int* in_sizes, int n_in,
                              void* d_out, int out_size, void* d_ws, size_t ws_size,
                              hipStream_t stream) {
    const float* x   = (const float*)d_in[0];
    const int*   ei  = (const int*)d_in[1];
    const float* W1  = (const float*)d_in[2];
    const float* b1  = (const float*)d_in[3];
    const float* W2  = (const float*)d_in[4];
    const float* b2  = (const float*)d_in[5];
    float*       out = (float*)d_out;

    const int* src = ei;
    const int* dst = ei + N_EDGES;

    char* ws = (char*)d_ws;
    size_t off = 0;
    auto alloc = [&](size_t bytes) {
        void* p = ws + off;
        off += (bytes + 255) & ~(size_t)255;
        return p;
    };

    // --- CSR-gather path layout ---
    unsigned int* cur  = (unsigned int*)alloc(N_NODES * sizeof(unsigned int));
    unsigned int* bsum = (unsigned int*)alloc(SCAN_NB * sizeof(unsigned int));
    float*        dinv = (float*)alloc(N_NODES * sizeof(float));
    int*          esrc = (int*)alloc((size_t)N_EDGES * sizeof(int));
    float*        h1   = (float*)alloc((size_t)N_NODES * HID_C * sizeof(float));
    float*        g1   = (float*)alloc((size_t)N_NODES * HID_C * sizeof(float));
    float*        h2   = h1;  // layer-2 GEMM output reuses h1's space
    size_t needed = off;

    if (ws_size >= needed) {
        // ---------------- CSR gather path (no float atomics) ----------------
        hipMemsetAsync(cur, 0, N_NODES * sizeof(unsigned int), stream);

        deg_kernel<<<(N_EDGES + 255) / 256, 256, 0, stream>>>(dst, cur, N_EDGES);
        scan1_kernel<<<SCAN_NB, 256, 0, stream>>>(cur, bsum, dinv, N_NODES);
        scan2_kernel<<<SCAN_NB, 256, 0, stream>>>(cur, bsum, N_NODES);
        fill_kernel<<<(N_EDGES + 255) / 256, 256, 0, stream>>>(src, dst, cur,
                                                               esrc, N_EDGES);
        // layer 1
        gemm_kernel<64, 128, 32, 4, 8, IN_C, HID_C>
            <<<(N_NODES + 63) / 64, 256, 0, stream>>>(x, W1, h1, N_NODES);
        {
            int total = N_NODES * (HID_C / 4);
            gather_kernel<HID_C, true>
                <<<(total + 255) / 256, 256, 0, stream>>>(cur, esrc, dinv, h1,
                                                          b1, g1, N_NODES);
        }
        // layer 2
        gemm_kernel<64, 64, 32, 4, 4, HID_C, OUT_C>
            <<<(N_NODES + 63) / 64, 256, 0, stream>>>(g1, W2, h2, N_NODES);
        {
            int total = N_NODES * (OUT_C / 4);
            gather_kernel<OUT_C, false>
                <<<(total + 255) / 256, 256, 0, stream>>>(cur, esrc, dinv, h2,
                                                          b2, out, N_NODES);
        }
    } else {
        // ---------------- fallback: proven atomic-scatter path --------------
        off = 0;
        unsigned int* deg   = (unsigned int*)alloc(N_NODES * sizeof(unsigned int));
        float*        dinvF = (float*)alloc(N_NODES * sizeof(float));
        float*        h1F   = (float*)alloc((size_t)N_NODES * HID_C * sizeof(float));
        float*        agg1  = (float*)alloc((size_t)N_NODES * HID_C * sizeof(float));
        float*        h2F   = h1F;

        hipMemsetAsync(deg, 0, N_NODES * sizeof(unsigned int), stream);
        hipMemsetAsync(agg1, 0, (size_t)N_NODES * HID_C * sizeof(float), stream);
        hipMemsetAsync(out, 0, (size_t)N_NODES * OUT_C * sizeof(float), stream);

        deg_kernel<<<(N_EDGES + 255) / 256, 256, 0, stream>>>(dst, deg, N_EDGES);
        dinv_only_kernel<<<(N_NODES + 255) / 256, 256, 0, stream>>>(deg, dinvF,
                                                                    N_NODES);

        gemm_kernel<64, 128, 32, 4, 8, IN_C, HID_C>
            <<<(N_NODES + 63) / 64, 256, 0, stream>>>(x, W1, h1F, N_NODES);
        {
            long long total = (long long)N_EDGES * (HID_C / 4);
            scatter_kernel<HID_C, HID_C / 4>
                <<<(unsigned)((total + 255) / 256), 256, 0, stream>>>(
                    src, dst, dinvF, h1F, agg1, N_EDGES);
        }
        {
            int total = N_NODES * (HID_C / 4);
            epilogue_kernel<HID_C, true>
                <<<(total + 255) / 256, 256, 0, stream>>>(agg1, h1F, dinvF, b1,
                                                          agg1, N_NODES);
        }
        gemm_kernel<64, 64, 32, 4, 4, HID_C, OUT_C>
            <<<(N_NODES + 63) / 64, 256, 0, stream>>>(agg1, W2, h2F, N_NODES);
        {
            long long total = (long long)N_EDGES * (OUT_C / 4);
            scatter_kernel<OUT_C, OUT_C / 4>
                <<<(unsigned)((total + 255) / 256), 256, 0, stream>>>(
                    src, dst, dinvF, h2F, out, N_EDGES);
        }
        {
            int total = N_NODES * (OUT_C / 4);
            epilogue_kernel<OUT_C, false>
                <<<(total + 255) / 256, 256, 0, stream>>>(out, h2F, dinvF, b2,
                                                          out, N_NODES);
        }
    }
}